// Round 6
// baseline (49.033 us; speedup 1.0000x reference)
//
#include <hip/hip_runtime.h>

// Problem constants (fixed by setup_inputs)
constexpr int B  = 32;
constexpr int M  = 512;    // entities per batch
constexpr int N  = 128;    // channels
constexpr int H  = 128;
constexpr int W  = 128;
constexpr int HW = H * W;            // 16384 = 2^14

typedef float f4 __attribute__((ext_vector_type(4)));
typedef int   i4 __attribute__((ext_vector_type(4)));

// ---------------------------------------------------------------------------
// Single fused kernel, occupancy-tuned.
// Grid: 32 b x 4 nh x 16 pc = 2048 blocks x 256 threads.
// Block: batch b, p-range [pc*1024, +1024), n-range [nh*32, +32).
// LDS 4 KB, target VGPR <= 64  ->  8 blocks/CU = 32 waves/CU.
//
// Phase 1: per-block inverse map for its p-range in LDS (loc slice is 4 KB,
//          L2-resident; each thread reads one i4 = 2 entities).
// Phase 2: thread owns p-quad; 4 source rows fixed for all 32 n.
//          4 groups x (8 hoisted f4 row-loads -> 8 coalesced f4 stores).
//          Invalid p -> row 0 (wave-broadcast L1 hit) + cndmask to 0.
// HBM: 256 MB store stream + ~10 MB compulsory reads.
// ---------------------------------------------------------------------------
__global__ __launch_bounds__(256)
void fused_scatter_kernel(const float* __restrict__ x,
                          const int* __restrict__ loc,
                          float* __restrict__ out) {
    __shared__ int lmap[1024];

    const int tid = threadIdx.x;
    const int bid = blockIdx.x;
    const int b  = bid >> 6;           // 64 blocks per batch
    const int nh = (bid >> 4) & 3;     // n-quarter
    const int pc = bid & 15;           // p-chunk
    const int n0 = nh << 5;            // 0,32,64,96
    const int p0 = pc << 10;

    // --- Phase 1: local inverse map ------------------------------------
    const i4 lv = *reinterpret_cast<const i4*>(loc + (b << 10) + (tid << 2));

    i4 neg = {-1, -1, -1, -1};
    *reinterpret_cast<i4*>(&lmap[tid << 2]) = neg;
    __syncthreads();

    const int f0 = (lv[0] << 7) + lv[1] - p0;   // y*W + x - p0
    const int f1 = (lv[2] << 7) + lv[3] - p0;
    if ((unsigned)f0 < 1024u) lmap[f0] = (tid << 1);
    if ((unsigned)f1 < 1024u) lmap[f1] = (tid << 1) + 1;
    __syncthreads();

    // --- Phase 2: gather + stream stores --------------------------------
    const i4 iv = *reinterpret_cast<const i4*>(&lmap[tid << 2]);
    const bool v0 = iv[0] >= 0, v1 = iv[1] >= 0, v2 = iv[2] >= 0, v3 = iv[3] >= 0;

    const float* xb = x + (b << 16) + n0;       // x[b, :, n0..], row stride 128
    const float* a0 = xb + ((v0 ? iv[0] : 0) << 7);
    const float* a1 = xb + ((v1 ? iv[1] : 0) << 7);
    const float* a2 = xb + ((v2 ? iv[2] : 0) << 7);
    const float* a3 = xb + ((v3 ? iv[3] : 0) << 7);

    float* ob = out + (b << 21) + (n0 << 14) + p0 + (tid << 2);

    #pragma unroll
    for (int g = 0; g < 4; ++g) {               // 4 groups of 8 channels
        f4 xv[2][4];
        #pragma unroll
        for (int q = 0; q < 2; ++q) {           // hoisted loads: 8 f4
            const int off = (g << 3) + (q << 2);
            xv[q][0] = *reinterpret_cast<const f4*>(a0 + off);
            xv[q][1] = *reinterpret_cast<const f4*>(a1 + off);
            xv[q][2] = *reinterpret_cast<const f4*>(a2 + off);
            xv[q][3] = *reinterpret_cast<const f4*>(a3 + off);
        }
        #pragma unroll
        for (int q = 0; q < 2; ++q) {
            float* o = ob + (((g << 3) + (q << 2)) << 14);
            #pragma unroll
            for (int j = 0; j < 4; ++j) {       // n = n0 + g*8 + q*4 + j
                f4 v = {v0 ? xv[q][0][j] : 0.f,
                        v1 ? xv[q][1][j] : 0.f,
                        v2 ? xv[q][2][j] : 0.f,
                        v3 ? xv[q][3][j] : 0.f};
                *reinterpret_cast<f4*>(o + (j << 14)) = v;
            }
        }
    }
}

// ---------------------------------------------------------------------------
extern "C" void kernel_launch(void* const* d_in, const int* in_sizes, int n_in,
                              void* d_out, int out_size, void* d_ws, size_t ws_size,
                              hipStream_t stream) {
    const float* x   = (const float*)d_in[0];
    const int*   loc = (const int*)d_in[1];
    float* out = (float*)d_out;

    fused_scatter_kernel<<<2048, 256, 0, stream>>>(x, loc, out);
}